// Round 5
// baseline (180.138 us; speedup 1.0000x reference)
//
#include <hip/hip_runtime.h>
#include <hip/hip_bf16.h>
#include <stdint.h>

// Problem dims
constexpr int NB = 4;          // batch
constexpr int NF = 16;         // frames
constexpr int NH = 224, NW = 224;
constexpr int HWPIX = NH * NW;             // 50176
constexpr int H1 = 112, W1 = 112;
constexpr int OC2 = 128;

typedef __attribute__((ext_vector_type(8))) __bf16 bf16x8;
typedef __attribute__((ext_vector_type(4))) float f32x4;

#define MFMA16(a, b, c) __builtin_amdgcn_mfma_f32_16x16x32_bf16(a, b, c, 0, 0, 0)

__device__ __forceinline__ void gload_lds16(const void* g, void* l) {
  __builtin_amdgcn_global_load_lds(
      (const __attribute__((address_space(1))) unsigned int*)g,
      (__attribute__((address_space(3))) unsigned int*)l, 16, 0, 0);
}

__device__ __forceinline__ ushort bf16u(float f) {
  __hip_bfloat16 h = __float2bfloat16(f);
  return *(ushort*)&h;
}

// ---------------- fused gray + uniform LBP codes (u8) + per-tile max ----------
__global__ __launch_bounds__(256) void graylbp_kernel(const float* __restrict__ x,
                                                      unsigned char* __restrict__ lbpc,
                                                      int* __restrict__ blockmax) {
  __shared__ float sg[18 * 18];
  const int tile = blockIdx.x;                          // 0..195
  const int frame = blockIdx.y;                         // 0..63
  const int ty = tile / 14, tx = tile - ty * 14;
  const int b = frame >> 4, f = frame & 15;
  const float* xb = x + ((size_t)b * 3 * NF + f) * HWPIX;   // channel stride NF*HWPIX

  for (int e = threadIdx.x; e < 324; e += 256) {
    int r = e / 18, cc = e - 18 * r;
    int y = ty * 16 + r - 1, xx = tx * 16 + cc - 1;
    float v = 0.0f;
    if ((unsigned)y < (unsigned)NH && (unsigned)xx < (unsigned)NW) {
      size_t o = (size_t)y * NW + xx;
      float s = xb[o] + xb[o + (size_t)NF * HWPIX] + xb[o + 2 * (size_t)NF * HWPIX];
      v = floorf((s / 3.0f) * 255.0f);
    }
    sg[e] = v;
  }
  __syncthreads();

  const int r = threadIdx.x >> 4, cc = threadIdx.x & 15;
  float n[3][3];
#pragma unroll
  for (int dy = 0; dy < 3; ++dy)
#pragma unroll
    for (int dx = 0; dx < 3; ++dx) n[dy][dx] = sg[(r + dy) * 18 + (cc + dx)];
  float c = n[1][1];

  constexpr double Ad = 0.70711;
  constexpr double Bd = 1.0 - Ad;

  const float s0 = n[1][2];
  const float s2 = n[0][1];
  const float s4 = n[1][0];
  const float s6 = n[2][1];
  const float s1 = (float)(Ad * Bd) * n[0][1] + (float)(Ad * Ad) * n[0][2]
                 + (float)(Bd * Bd) * n[1][1] + (float)(Bd * Ad) * n[1][2];
  const float s3 = (float)(Ad * Ad) * n[0][0] + (float)(Ad * Bd) * n[0][1]
                 + (float)(Bd * Ad) * n[1][0] + (float)(Bd * Bd) * n[1][1];
  const float s5 = (float)(Bd * Ad) * n[1][0] + (float)(Bd * Bd) * n[1][1]
                 + (float)(Ad * Ad) * n[2][0] + (float)(Ad * Bd) * n[2][1];
  const float s7 = (float)(Bd * Bd) * n[1][1] + (float)(Bd * Ad) * n[1][2]
                 + (float)(Ad * Bd) * n[2][1] + (float)(Ad * Ad) * n[2][2];

  bool bb[8] = { s0 >= c, s1 >= c, s2 >= c, s3 >= c,
                 s4 >= c, s5 >= c, s6 >= c, s7 >= c };
  int ones = 0, changes = 0;
#pragma unroll
  for (int p = 0; p < 8; ++p) {
    ones += bb[p] ? 1 : 0;
    changes += (bb[p] != bb[(p + 1) & 7]) ? 1 : 0;
  }
  int code = (changes <= 2) ? ones : 9;
  lbpc[(size_t)frame * HWPIX + (ty * 16 + r) * NW + tx * 16 + cc] = (unsigned char)code;

  int m = code;
#pragma unroll
  for (int off = 32; off >= 1; off >>= 1) m = max(m, __shfl_down(m, off, 64));
  __shared__ int wm[4];
  if ((threadIdx.x & 63) == 0) wm[threadIdx.x >> 6] = m;
  __syncthreads();
  if (threadIdx.x == 0)
    blockmax[frame * 196 + tile] = max(max(wm[0], wm[1]), max(wm[2], wm[3]));
}

// ---------------- per-frame max + normalization LUT (bf16) ----------------
__global__ void framemax_tab_kernel(const int* __restrict__ blockmax,
                                    __hip_bfloat16* __restrict__ normtab) {
  int t = threadIdx.x;                                   // 256
  int f = t >> 2, part = t & 3;
  int m = 0;
  for (int j = part; j < 196; j += 4) m = max(m, blockmax[f * 196 + j]);
  m = max(m, __shfl_xor(m, 1, 64));
  m = max(m, __shfl_xor(m, 2, 64));
  if (part == 0) {
    for (int cde = 0; cde < 16; ++cde) {
      float v = (m > 0) ? ((float)cde / (float)m) : (float)cde;  // exact f32 div like ref
      normtab[f * 16 + cde] = __float2bfloat16(v);
    }
  }
}

// -------- w1r[oc][32] bf16 (+ zero the 128B pad page for conv2 staging) -------
__global__ void w1r_kernel(const float* __restrict__ w1, const float* __restrict__ b1,
                           __hip_bfloat16* __restrict__ w1r, float* __restrict__ zpage) {
  int o = threadIdx.x;
  if (o >= 64) {
    if (o < 96) zpage[o - 64] = 0.0f;                    // 128B zero page
    return;
  }
  for (int k = 0; k < 32; ++k) {
    float v;
    if (k < 27)      v = w1[o * 81 + k] + w1[o * 81 + 27 + k] + w1[o * 81 + 54 + k];
    else if (k == 27) v = b1[o];
    else              v = 0.0f;
    w1r[o * 32 + k] = __float2bfloat16(v);
  }
}

// ---------------- w2r[tap][oc][ic] (bf16) from w2[oc][ic][27] ----------------
__global__ __launch_bounds__(256) void w2r_kernel(const float* __restrict__ w2,
                                                  __hip_bfloat16* __restrict__ w2r) {
  int i = blockIdx.x * 256 + threadIdx.x;
  if (i >= 27 * 128 * 64) return;
  int tap = i / (128 * 64);
  int rem = i - tap * (128 * 64);
  int oc = rem >> 6, ic = rem & 63;
  w2r[i] = __float2bfloat16(w2[((size_t)oc * 64 + ic) * 27 + tap]);
}

// ---------------- conv1 as MFMA implicit GEMM --------------------------------
__global__ __launch_bounds__(256, 2) void conv1_mfma(
    const unsigned char* __restrict__ lbpc,
    const __hip_bfloat16* __restrict__ normtab,
    const __hip_bfloat16* __restrict__ w1r,
    __hip_bfloat16* __restrict__ h1) {
  __shared__ ushort stab[48];
  __shared__ __align__(16) ushort tile[3 * 9 * 240];     // 12,960 B
  __shared__ __align__(16) ushort epi[448 * 64];         // 57,344 B

  const int g = blockIdx.x;                              // 0..27 (y1 = 4g..4g+3)
  const int bf = blockIdx.y;                             // 0..63
  const int b = bf >> 4, f1 = bf & 15;
  const int tid = threadIdx.x;
  const int lane = tid & 63, w = tid >> 6;               // wave w owns y1-row 4g+w
  const int c = lane & 15, q = lane >> 4;

  if (tid < 48) {
    int kf = tid >> 4;
    int fin = f1 - 1 + kf;
    stab[tid] = ((unsigned)fin < (unsigned)NF)
        ? ((const ushort*)normtab)[(b * NF + fin) * 16 + (tid & 15)] : (ushort)0;
  }
  __syncthreads();

  for (int idx = tid; idx < 3 * 9 * 240; idx += 256) {
    int kf = idx / 2160;
    int rem = idx - kf * 2160;
    int row = rem / 240;
    int xx = rem - row * 240;
    int fin = f1 - 1 + kf;
    int yin = 8 * g - 1 + row;
    int xin = xx - 1;
    ushort v = 0;
    if ((unsigned)fin < (unsigned)NF && (unsigned)yin < (unsigned)NH &&
        (unsigned)xin < (unsigned)NW) {
      int code = lbpc[((size_t)(b * NF + fin)) * HWPIX + yin * NW + xin];
      v = stab[kf * 16 + code];
    }
    tile[idx] = v;
  }

  bf16x8 afr[4];
  const __bf16* w1rb = (const __bf16*)w1r;
#pragma unroll
  for (int ocg = 0; ocg < 4; ++ocg)
    afr[ocg] = *(const bf16x8*)(w1rb + ((ocg * 16 + c) << 5) + q * 8);

  int pre[8]; ushort fb[8]; bool vld[8];
#pragma unroll
  for (int j = 0; j < 8; ++j) {
    int k = q * 8 + j;
    vld[j] = (k < 27);
    fb[j] = (k == 27) ? (ushort)0x3F80 : (ushort)0;      // bias lane: input 1.0
    int kf = k / 9, r9 = k - 9 * kf;
    int ky = r9 / 3, kx = r9 - 3 * ky;
    pre[j] = kf * 2160 + (2 * w + ky) * 240 + kx + 2 * c;
  }

  __syncthreads();

  const f32x4 zero4 = {0.f, 0.f, 0.f, 0.f};
  for (int fx = 0; fx < 7; ++fx) {
    union { bf16x8 v; ushort u[8]; } bu;
#pragma unroll
    for (int j = 0; j < 8; ++j)
      bu.u[j] = vld[j] ? tile[pre[j] + 32 * fx] : fb[j];

    const int posl = w * 112 + fx * 16 + c;
    const int swz = (posl & 7) << 4;
    const int ebase = posl * 128 + q * 8;
#pragma unroll
    for (int ocg = 0; ocg < 4; ++ocg) {
      f32x4 acc = MFMA16(afr[ocg], bu.v, zero4);
      ushort4 o;
      o.x = bf16u(fmaxf(acc[0], 0.0f));
      o.y = bf16u(fmaxf(acc[1], 0.0f));
      o.z = bf16u(fmaxf(acc[2], 0.0f));
      o.w = bf16u(fmaxf(acc[3], 0.0f));
      *(ushort4*)((char*)epi + ((ebase + ocg * 32) ^ swz)) = o;
    }
  }
  __syncthreads();

  const size_t blockbase = ((size_t)(bf * H1 + 4 * g) * W1) * 128;
  char* h1b = (char*)h1;
  const char* epb = (const char*)epi;
  for (int m = tid; m < 3584; m += 256) {
    int byte = m * 16;
    int posl = m >> 3;
    int src = byte ^ ((posl & 7) << 4);
    *(int4*)(h1b + blockbase + byte) = *(const int4*)(epb + src);
  }
}

// ---------------- conv2: pipelined implicit-GEMM MFMA -------------------------
// 6 stages per block: (kf 0..2) x (ic-half 0..1). Double-buffered 36,480B slabs,
// T3 2-phase: issue stage s+1's global_load_lds, compute stage s, barrier.
// LDS layout per stage: row r(0..4) x t(0..56, = xs>>1) 128B units; granule
// g = (xs&1)*4 + ic_granule stored at slot g^(t&7) (bank-spread, 2-way floor).
constexpr int ROWB = 57 * 128;             // 7,296 B
constexpr int BUFB = 5 * ROWB;             // 36,480 B

__global__ __launch_bounds__(256, 2) void conv2_mfma(
    const __hip_bfloat16* __restrict__ h1,
    const __hip_bfloat16* __restrict__ w2r,
    const float* __restrict__ b2,
    const float* __restrict__ zpage,
    float* __restrict__ partial) {
  __shared__ __align__(16) char slab[2 * BUFB];          // 72,960 B

  const int gg = blockIdx.x;                             // 0..27 (y2 pair)
  const int f2 = blockIdx.y;                             // 0..7
  const int b = blockIdx.z;                              // 0..3
  const int tid = threadIdx.x;
  const int lane = tid & 63, wid = tid >> 6;
  const int c = lane & 15, q = lane >> 4;
  const int oc0 = wid * 32;
  const int dt = lane >> 3, sl = lane & 7;               // staging decode

  int x2v[7], rbase[7];
#pragma unroll
  for (int j = 0; j < 7; ++j) {
    int pos = j * 16 + c;
    int yo = pos >= 56 ? 1 : 0;
    x2v[j] = pos - 56 * yo;
    rbase[j] = yo * 2 * ROWB + x2v[j] * 128;
  }

  float bias[2][4];
#pragma unroll
  for (int i = 0; i < 2; ++i)
#pragma unroll
    for (int r = 0; r < 4; ++r) bias[i][r] = b2[oc0 + i * 16 + q * 4 + r];

  f32x4 acc[2][7];
#pragma unroll
  for (int i = 0; i < 2; ++i)
#pragma unroll
    for (int j = 0; j < 7; ++j) acc[i][j] = f32x4{0.f, 0.f, 0.f, 0.f};

  const char* h1b = (const char*)h1;
  const char* zp = (const char*)zpage;
  const __bf16* w2rb = (const __bf16*)w2r;

  auto STAGE = [&](int s) {
    const int kf = s >> 1, ich = s & 1;
    const int f1 = 2 * f2 - 1 + kf;
    const bool fok = (unsigned)f1 < (unsigned)NF;
    char* buf = slab + (s & 1) * BUFB;
    for (int task = wid; task < 40; task += 4) {
      const int r = task >> 3, cch = task & 7;
      const int y1 = 4 * gg - 1 + r;
      const int t = cch * 8 + dt;                        // 0..63
      const int g8 = sl ^ (t & 7);
      const int xs = 2 * t + (g8 >> 2);
      const int gr = g8 & 3;
      const char* gsrc;
      if (fok && (unsigned)y1 < (unsigned)H1 && (unsigned)(xs - 1) < (unsigned)W1) {
        gsrc = h1b + ((((size_t)(b * NF + f1) * H1 + y1) * W1 + (xs - 1)) << 7)
             + ich * 64 + (gr << 4);
      } else {
        gsrc = zp;                                       // zero page
      }
      gload_lds16(gsrc, buf + r * ROWB + cch * 1024);
    }
  };

  STAGE(0);
  __syncthreads();

#pragma unroll 1
  for (int s = 0; s < 6; ++s) {
    if (s < 5) STAGE(s + 1);

    const int kf = s >> 1, ich = s & 1;
    const char* buf = slab + (s & 1) * BUFB;
#pragma unroll
    for (int ky = 0; ky < 3; ++ky) {
#pragma unroll
      for (int kx = 0; kx < 3; ++kx) {
        const int tap = kf * 9 + ky * 3 + kx;
        const __bf16* wtap = w2rb + (((size_t)tap * 128 + oc0 + c) << 6)
                           + ich * 32 + q * 8;
        bf16x8 a0 = *(const bf16x8*)(wtap);
        bf16x8 a1 = *(const bf16x8*)(wtap + (16 << 6));
        const int sx = kx >> 1;
        const int gb = (kx & 1) * 4 + q;
        const int imm = ky * ROWB + sx * 128;
#pragma unroll
        for (int j = 0; j < 7; ++j) {
          const int s8 = gb ^ ((x2v[j] + sx) & 7);
          bf16x8 bv = *(const bf16x8*)(buf + rbase[j] + imm + (s8 << 4));
          acc[0][j] = MFMA16(a0, bv, acc[0][j]);
          acc[1][j] = MFMA16(a1, bv, acc[1][j]);
        }
      }
    }
    __syncthreads();   // drains vmcnt(0): stage s+1 loads complete; buf swap safe
  }

  // ---- epilogue: bias + relu + pool over 112 positions, reduce 16 lanes ----
#pragma unroll
  for (int i = 0; i < 2; ++i) {
#pragma unroll
    for (int r = 0; r < 4; ++r) {
      float s = 0.0f;
#pragma unroll
      for (int j = 0; j < 7; ++j) s += fmaxf(acc[i][j][r] + bias[i][r], 0.0f);
      s += __shfl_xor(s, 1);
      s += __shfl_xor(s, 2);
      s += __shfl_xor(s, 4);
      s += __shfl_xor(s, 8);
      if (c == 0) {
        int oc = oc0 + i * 16 + q * 4 + r;
        partial[((size_t)b * OC2 + oc) * 224 + f2 * 28 + gg] = s;
      }
    }
  }
}

__global__ void final_kernel(const float* __restrict__ partial, float* __restrict__ out) {
  int i = blockIdx.x * 256 + threadIdx.x;                // < 512
  float s = 0.0f;
  for (int j = 0; j < 224; ++j) s += partial[(size_t)i * 224 + j];
  out[i] = s / 25088.0f;
}

extern "C" void kernel_launch(void* const* d_in, const int* in_sizes, int n_in,
                              void* d_out, int out_size, void* d_ws, size_t ws_size,
                              hipStream_t stream) {
  const float* x  = (const float*)d_in[0];
  const float* w1 = (const float*)d_in[1];
  const float* b1 = (const float*)d_in[2];
  const float* w2 = (const float*)d_in[3];
  const float* b2 = (const float*)d_in[4];
  float* out = (float*)d_out;

  char* ws = (char*)d_ws;
  __hip_bfloat16* h1 = (__hip_bfloat16*)ws;                    // 102,760,448 B
  unsigned char* lbpc = (unsigned char*)(ws + 102760448);      // 3,211,264 B
  int* blockmax = (int*)(ws + 105971712);                      // 50,176 B
  __hip_bfloat16* normtab = (__hip_bfloat16*)(ws + 106021888); // 2,048 B
  float* partial = (float*)(ws + 106023936);                   // 458,752 B
  __hip_bfloat16* w2r = (__hip_bfloat16*)(ws + 106482688);     // 442,368 B
  __hip_bfloat16* w1r = (__hip_bfloat16*)(ws + 106925056);     // 4,096 B
  float* zpage = (float*)(ws + 106929152);                     // 256 B -> 106,929,408

  w1r_kernel<<<1, 128, 0, stream>>>(w1, b1, w1r, zpage);
  w2r_kernel<<<(27 * 128 * 64 + 255) / 256, 256, 0, stream>>>(w2, w2r);
  graylbp_kernel<<<dim3(196, NB * NF), 256, 0, stream>>>(x, lbpc, blockmax);
  framemax_tab_kernel<<<1, 256, 0, stream>>>(blockmax, normtab);
  conv1_mfma<<<dim3(28, NB * NF), 256, 0, stream>>>(lbpc, normtab, w1r, h1);
  conv2_mfma<<<dim3(28, 8, 4), 256, 0, stream>>>(h1, w2r, b2, zpage, partial);
  final_kernel<<<2, 256, 0, stream>>>(partial, out);
}

// Round 7
// 135.102 us; speedup vs baseline: 1.3334x; 1.3334x over previous
//
#include <hip/hip_runtime.h>
#include <hip/hip_bf16.h>
#include <stdint.h>

// Problem dims
constexpr int NB = 4;          // batch
constexpr int NF = 16;         // frames
constexpr int NH = 224, NW = 224;
constexpr int HWPIX = NH * NW;             // 50176
constexpr int OC2 = 128;

typedef __attribute__((ext_vector_type(8))) __bf16 bf16x8;
typedef __attribute__((ext_vector_type(4))) float f32x4;

#define MFMA16(a, b, c) __builtin_amdgcn_mfma_f32_16x16x32_bf16(a, b, c, 0, 0, 0)

__device__ __forceinline__ ushort bf16u(float f) {
  __hip_bfloat16 h = __float2bfloat16(f);
  return *(ushort*)&h;
}

// ---------------- fused gray + uniform LBP codes (u8) + per-tile max ----------
__global__ __launch_bounds__(256) void graylbp_kernel(const float* __restrict__ x,
                                                      unsigned char* __restrict__ lbpc,
                                                      int* __restrict__ blockmax) {
  __shared__ float sg[18 * 18];
  const int tile = blockIdx.x;                          // 0..195
  const int frame = blockIdx.y;                         // 0..63
  const int ty = tile / 14, tx = tile - ty * 14;
  const int b = frame >> 4, f = frame & 15;
  const float* xb = x + ((size_t)b * 3 * NF + f) * HWPIX;   // channel stride NF*HWPIX

  for (int e = threadIdx.x; e < 324; e += 256) {
    int r = e / 18, cc = e - 18 * r;
    int y = ty * 16 + r - 1, xx = tx * 16 + cc - 1;
    float v = 0.0f;
    if ((unsigned)y < (unsigned)NH && (unsigned)xx < (unsigned)NW) {
      size_t o = (size_t)y * NW + xx;
      float s = xb[o] + xb[o + (size_t)NF * HWPIX] + xb[o + 2 * (size_t)NF * HWPIX];
      v = floorf((s / 3.0f) * 255.0f);
    }
    sg[e] = v;
  }
  __syncthreads();

  const int r = threadIdx.x >> 4, cc = threadIdx.x & 15;
  float n[3][3];
#pragma unroll
  for (int dy = 0; dy < 3; ++dy)
#pragma unroll
    for (int dx = 0; dx < 3; ++dx) n[dy][dx] = sg[(r + dy) * 18 + (cc + dx)];
  float c = n[1][1];

  constexpr double Ad = 0.70711;
  constexpr double Bd = 1.0 - Ad;

  const float s0 = n[1][2];
  const float s2 = n[0][1];
  const float s4 = n[1][0];
  const float s6 = n[2][1];
  const float s1 = (float)(Ad * Bd) * n[0][1] + (float)(Ad * Ad) * n[0][2]
                 + (float)(Bd * Bd) * n[1][1] + (float)(Bd * Ad) * n[1][2];
  const float s3 = (float)(Ad * Ad) * n[0][0] + (float)(Ad * Bd) * n[0][1]
                 + (float)(Bd * Ad) * n[1][0] + (float)(Bd * Bd) * n[1][1];
  const float s5 = (float)(Bd * Ad) * n[1][0] + (float)(Bd * Bd) * n[1][1]
                 + (float)(Ad * Ad) * n[2][0] + (float)(Ad * Bd) * n[2][1];
  const float s7 = (float)(Bd * Bd) * n[1][1] + (float)(Bd * Ad) * n[1][2]
                 + (float)(Ad * Bd) * n[2][1] + (float)(Ad * Ad) * n[2][2];

  bool bb[8] = { s0 >= c, s1 >= c, s2 >= c, s3 >= c,
                 s4 >= c, s5 >= c, s6 >= c, s7 >= c };
  int ones = 0, changes = 0;
#pragma unroll
  for (int p = 0; p < 8; ++p) {
    ones += bb[p] ? 1 : 0;
    changes += (bb[p] != bb[(p + 1) & 7]) ? 1 : 0;
  }
  int code = (changes <= 2) ? ones : 9;
  lbpc[(size_t)frame * HWPIX + (ty * 16 + r) * NW + tx * 16 + cc] = (unsigned char)code;

  int m = code;
#pragma unroll
  for (int off = 32; off >= 1; off >>= 1) m = max(m, __shfl_down(m, off, 64));
  __shared__ int wm[4];
  if ((threadIdx.x & 63) == 0) wm[threadIdx.x >> 6] = m;
  __syncthreads();
  if (threadIdx.x == 0)
    blockmax[frame * 196 + tile] = max(max(wm[0], wm[1]), max(wm[2], wm[3]));
}

// ---------------- per-frame max + normalization LUT (bf16) ----------------
__global__ void framemax_tab_kernel(const int* __restrict__ blockmax,
                                    __hip_bfloat16* __restrict__ normtab) {
  int t = threadIdx.x;                                   // 256
  int f = t >> 2, part = t & 3;
  int m = 0;
  for (int j = part; j < 196; j += 4) m = max(m, blockmax[f * 196 + j]);
  m = max(m, __shfl_xor(m, 1, 64));
  m = max(m, __shfl_xor(m, 2, 64));
  if (part == 0) {
    for (int cde = 0; cde < 16; ++cde) {
      float v = (m > 0) ? ((float)cde / (float)m) : (float)cde;  // exact f32 div like ref
      normtab[f * 16 + cde] = __float2bfloat16(v);
    }
  }
}

// -------- w1r[oc][32] bf16: 27 summed-channel taps + bias@27 + pad ------------
__global__ void w1r_kernel(const float* __restrict__ w1, const float* __restrict__ b1,
                           __hip_bfloat16* __restrict__ w1r) {
  int o = threadIdx.x;
  if (o >= 64) return;
  for (int k = 0; k < 32; ++k) {
    float v;
    if (k < 27)      v = w1[o * 81 + k] + w1[o * 81 + 27 + k] + w1[o * 81 + 54 + k];
    else if (k == 27) v = b1[o];
    else              v = 0.0f;
    w1r[o * 32 + k] = __float2bfloat16(v);
  }
}

// ---------------- w2r[tap][oc][ic] (bf16) from w2[oc][ic][27] ----------------
__global__ __launch_bounds__(256) void w2r_kernel(const float* __restrict__ w2,
                                                  __hip_bfloat16* __restrict__ w2r) {
  int i = blockIdx.x * 256 + threadIdx.x;
  if (i >= 27 * 128 * 64) return;
  int tap = i / (128 * 64);
  int rem = i - tap * (128 * 64);
  int oc = rem >> 6, ic = rem & 63;
  w2r[i] = __float2bfloat16(w2[((size_t)oc * 64 + ic) * 27 + tap]);
}

// ---------------- fused conv1+conv2 MFMA + bias/relu/pool ---------------------
// block = (gg y2-pair, f2, b). Per kf phase: conv1 (MFMA from u8 LBP codes,
// per-frame LUT bf16(code/m) applied at gather) builds the h1 slab in LDS;
// conv2 (MFMA) consumes it.
// Slab layout: y1-row r (0..4), xs (0..112): t=xs>>1, sub=xs&1; 64-ic bytes:
// ich half (128B) x granule gr (16B); g8=sub*4+gr stored at slot g8^(t&7).
constexpr int ROWB2 = 57 * 256;            // 14,592 B per y1-row
constexpr int LSTR = 232;                  // ltile row stride: [4B zero pad][224 data][4B tail]
constexpr int LT_TASKS = 3 * 11 * 58;      // u32 fill tasks (58 u32/row incl pads)

__global__ __launch_bounds__(256, 2) void fused_conv(
    const unsigned char* __restrict__ lbpc,
    const __hip_bfloat16* __restrict__ normtab,
    const __hip_bfloat16* __restrict__ w1r,
    const __hip_bfloat16* __restrict__ w2r,
    const float* __restrict__ b2,
    float* __restrict__ partial) {
  __shared__ __align__(16) char slab[5 * ROWB2];        // 72,960 B
  __shared__ __align__(4) unsigned char ltile[3 * 11 * LSTR];  // 7,656 B
  __shared__ ushort stabL[80];                           // 5 frames x 16 codes

  const int gg = blockIdx.x;                             // 0..27 (y2 pair)
  const int f2 = blockIdx.y;                             // 0..7
  const int b = blockIdx.z;                              // 0..3
  const int tid = threadIdx.x;
  const int lane = tid & 63, w = tid >> 6;
  const int c = lane & 15, q = lane >> 4;
  const int oc0 = w * 32;
  const f32x4 zero4 = {0.f, 0.f, 0.f, 0.f};

  // stab: frames fin = 2*f2-2+u, u=0..4 (covers f1-1+kfc for all kf phases)
  if (tid < 80) {
    int u = tid >> 4, cde = tid & 15;
    int fin = 2 * f2 - 2 + u;
    stabL[tid] = ((unsigned)fin < (unsigned)NF)
        ? ((const ushort*)normtab)[(b * NF + fin) * 16 + cde] : (ushort)0;
  }

  // conv2 per-j decode
  int x2v[7], rb2[7];
#pragma unroll
  for (int j = 0; j < 7; ++j) {
    int pos = j * 16 + c;
    int yo = pos >= 56 ? 1 : 0;
    x2v[j] = pos - 56 * yo;
    rb2[j] = yo * 2 * ROWB2 + x2v[j] * 256;
  }

  // conv1 A fragments
  bf16x8 afr[4];
  const __bf16* w1rb = (const __bf16*)w1r;
#pragma unroll
  for (int ocg = 0; ocg < 4; ++ocg)
    afr[ocg] = *(const bf16x8*)(w1rb + ((ocg * 16 + c) << 5) + q * 8);

  // conv1 gather precompute: k = q*8+e -> (kfc,ky,kx); pad byte handles x_in=-1
  int pre[8], se[8]; bool vld[8]; ushort fbv[8];
#pragma unroll
  for (int e = 0; e < 8; ++e) {
    int k = q * 8 + e;
    vld[e] = (k < 27);
    fbv[e] = (k == 27) ? (ushort)0x3F80 : (ushort)0;
    int kk = vld[e] ? k : 0;
    int kfc = kk / 9, r9 = kk - 9 * kfc;
    int ky = r9 / 3, kx = r9 - 3 * ky;
    pre[e] = (kfc * 11 + ky) * LSTR + 4 + (2 * c - 1 + kx);   // may be rowbase+3 (zero pad)
    se[e] = kfc * 16;
  }

  float bias[2][4];
#pragma unroll
  for (int i = 0; i < 2; ++i)
#pragma unroll
    for (int r = 0; r < 4; ++r) bias[i][r] = b2[oc0 + i * 16 + q * 4 + r];

  f32x4 acc[2][7];
#pragma unroll
  for (int i = 0; i < 2; ++i)
#pragma unroll
    for (int j = 0; j < 7; ++j) acc[i][j] = zero4;

  const __bf16* w2rb = (const __bf16*)w2r;

  // zero the static xs=0 pad cells
  if (tid < 40) {
    int r = tid >> 3, u = tid & 7;
    *(int4*)(slab + r * ROWB2 + (u >> 2) * 128 + (u & 3) * 16) = make_int4(0, 0, 0, 0);
  }

  // ---- ltile fill (direct) for phase kf: rows = [kfc 0..2][yrow 0..10] ----
  auto FILL = [&](int kf) {
    const int f1 = 2 * f2 - 1 + kf;
    for (int idx = tid; idx < LT_TASKS; idx += 256) {
      int kfc = idx / 638, rem = idx - kfc * 638;        // 11*58
      int row = rem / 58, chunk = rem - row * 58;
      uint32_t v = 0;
      if (chunk >= 1 && chunk <= 56) {
        int fin = f1 - 1 + kfc, yin = 8 * gg - 3 + row;
        if ((unsigned)fin < (unsigned)NF && (unsigned)yin < (unsigned)NH)
          v = *(const uint32_t*)(lbpc + (size_t)(b * NF + fin) * HWPIX + yin * NW + (chunk - 1) * 4);
      }
      *(uint32_t*)(ltile + (kfc * 11 + row) * LSTR + chunk * 4) = v;
    }
  };

  // ---- conv1 phase: build slab from ltile codes (LUT via stabL) ----
  auto CONV1 = [&](int kf) {
    const int f1 = 2 * f2 - 1 + kf;
    if ((unsigned)f1 >= (unsigned)NF) return;            // slab unread this phase
    const int koff = kf * 16;
    for (int fi = w; fi < 35; fi += 4) {
      int rr = fi / 7, fx = fi - 7 * rr;                 // y1 = 4gg-1+rr, x1 = fx*16+c
      int y1 = 4 * gg - 1 + rr;
      int xs = fx * 16 + c + 1;
      int t = xs >> 1, k7 = t & 7, sub = xs & 1;
      char* wbase = slab + rr * ROWB2 + t * 256 + (q & 1) * 8;
      if ((unsigned)y1 < 112u) {
        union { bf16x8 v; ushort u[8]; } bu;
        int foff = rr * (2 * LSTR) + fx * 32;
#pragma unroll
        for (int e = 0; e < 8; ++e) {
          int code = ltile[pre[e] + foff];
          bu.u[e] = vld[e] ? stabL[koff + se[e] + code] : fbv[e];
        }
#pragma unroll
        for (int ocg = 0; ocg < 4; ++ocg) {
          f32x4 a = MFMA16(afr[ocg], bu.v, zero4);
          ushort4 o;
          o.x = bf16u(fmaxf(a[0], 0.0f));
          o.y = bf16u(fmaxf(a[1], 0.0f));
          o.z = bf16u(fmaxf(a[2], 0.0f));
          o.w = bf16u(fmaxf(a[3], 0.0f));
          int ich = ocg >> 1;
          int g8 = sub * 4 + (ocg & 1) * 2 + (q >> 1);
          *(ushort4*)(wbase + ich * 128 + ((g8 ^ k7) << 4)) = o;
        }
      } else {
        ushort4 z; z.x = z.y = z.z = z.w = 0;
#pragma unroll
        for (int ocg = 0; ocg < 4; ++ocg) {
          int ich = ocg >> 1;
          int g8 = sub * 4 + (ocg & 1) * 2 + (q >> 1);
          *(ushort4*)(wbase + ich * 128 + ((g8 ^ k7) << 4)) = z;
        }
      }
    }
  };

  FILL(0);
  __syncthreads();
  CONV1(0);

  for (int kf = 0; kf < 3; ++kf) {
    __syncthreads();                                     // slab(kf) ready
    const int f1 = 2 * f2 - 1 + kf;
    const bool fok = (unsigned)f1 < (unsigned)NF;

    // T14: issue next phase's ltile loads into regs (latency hides under conv2)
    uint32_t fv[8];
    if (kf < 2) {
      const int f1n = f1 + 1;
#pragma unroll
      for (int i = 0; i < 8; ++i) {
        int idx = tid + i * 256;
        uint32_t v = 0;
        if (idx < LT_TASKS) {
          int kfc = idx / 638, rem = idx - kfc * 638;
          int row = rem / 58, chunk = rem - row * 58;
          if (chunk >= 1 && chunk <= 56) {
            int fin = f1n - 1 + kfc, yin = 8 * gg - 3 + row;
            if ((unsigned)fin < (unsigned)NF && (unsigned)yin < (unsigned)NH)
              v = *(const uint32_t*)(lbpc + (size_t)(b * NF + fin) * HWPIX + yin * NW + (chunk - 1) * 4);
          }
        }
        fv[i] = v;
      }
    }

    // ---- conv2 phase: consume slab ----
    if (fok) {
#pragma unroll
      for (int ky = 0; ky < 3; ++ky) {
#pragma unroll
        for (int kx = 0; kx < 3; ++kx) {
          const int tap = kf * 9 + ky * 3 + kx;
          const int sx = kx >> 1;
          const int sb4 = (kx & 1) * 4 + q;
          const int immr = ky * ROWB2 + sx * 256;
#pragma unroll
          for (int ich = 0; ich < 2; ++ich) {
            const __bf16* wtap = w2rb + (((size_t)tap * 128 + oc0 + c) << 6)
                               + ich * 32 + q * 8;
            bf16x8 a0 = *(const bf16x8*)(wtap);
            bf16x8 a1 = *(const bf16x8*)(wtap + (16 << 6));
#pragma unroll
            for (int j = 0; j < 7; ++j) {
              int slot = sb4 ^ ((x2v[j] + sx) & 7);
              bf16x8 bv = *(const bf16x8*)(slab + rb2[j] + immr + ich * 128 + (slot << 4));
              acc[0][j] = MFMA16(a0, bv, acc[0][j]);
              acc[1][j] = MFMA16(a1, bv, acc[1][j]);
            }
          }
        }
      }
    }

    if (kf < 2) {
#pragma unroll
      for (int i = 0; i < 8; ++i) {
        int idx = tid + i * 256;
        if (idx < LT_TASKS) {
          int kfc = idx / 638, rem = idx - kfc * 638;
          int row = rem / 58, chunk = rem - row * 58;
          *(uint32_t*)(ltile + (kfc * 11 + row) * LSTR + chunk * 4) = fv[i];
        }
      }
    }
    __syncthreads();                                     // slab reads + ltile update done
    if (kf < 2) CONV1(kf + 1);
  }

  // ---- epilogue: bias + relu + pool over 112 positions, reduce 16 lanes ----
#pragma unroll
  for (int i = 0; i < 2; ++i) {
#pragma unroll
    for (int r = 0; r < 4; ++r) {
      float s = 0.0f;
#pragma unroll
      for (int j = 0; j < 7; ++j) s += fmaxf(acc[i][j][r] + bias[i][r], 0.0f);
      s += __shfl_xor(s, 1);
      s += __shfl_xor(s, 2);
      s += __shfl_xor(s, 4);
      s += __shfl_xor(s, 8);
      if (c == 0) {
        int oc = oc0 + i * 16 + q * 4 + r;
        partial[((size_t)b * OC2 + oc) * 224 + f2 * 28 + gg] = s;
      }
    }
  }
}

__global__ void final_kernel(const float* __restrict__ partial, float* __restrict__ out) {
  int i = blockIdx.x * 256 + threadIdx.x;                // < 512
  float s = 0.0f;
  for (int j = 0; j < 224; ++j) s += partial[(size_t)i * 224 + j];
  out[i] = s / 25088.0f;
}

extern "C" void kernel_launch(void* const* d_in, const int* in_sizes, int n_in,
                              void* d_out, int out_size, void* d_ws, size_t ws_size,
                              hipStream_t stream) {
  const float* x  = (const float*)d_in[0];
  const float* w1 = (const float*)d_in[1];
  const float* b1 = (const float*)d_in[2];
  const float* w2 = (const float*)d_in[3];
  const float* b2 = (const float*)d_in[4];
  float* out = (float*)d_out;

  char* ws = (char*)d_ws;
  unsigned char* lbpc = (unsigned char*)ws;                    // 3,211,264 B
  int* blockmax = (int*)(ws + 3211264);                        // 50,176 B
  __hip_bfloat16* normtab = (__hip_bfloat16*)(ws + 3261440);   // 2,048 B
  float* partial = (float*)(ws + 3263488);                     // 458,752 B
  __hip_bfloat16* w2r = (__hip_bfloat16*)(ws + 3722240);       // 442,368 B
  __hip_bfloat16* w1r = (__hip_bfloat16*)(ws + 4164608);       // 4,096 B -> 4,168,704

  w1r_kernel<<<1, 64, 0, stream>>>(w1, b1, w1r);
  w2r_kernel<<<(27 * 128 * 64 + 255) / 256, 256, 0, stream>>>(w2, w2r);
  graylbp_kernel<<<dim3(196, NB * NF), 256, 0, stream>>>(x, lbpc, blockmax);
  framemax_tab_kernel<<<1, 256, 0, stream>>>(blockmax, normtab);
  fused_conv<<<dim3(28, 8, 4), 256, 0, stream>>>(lbpc, normtab, w1r, w2r, b2, partial);
  final_kernel<<<2, 256, 0, stream>>>(partial, out);
}